// Round 1
// baseline (1699.148 us; speedup 1.0000x reference)
//
#include <hip/hip_runtime.h>
#include <hip/hip_bf16.h>
#include <cstdint>
#include <cstddef>

// Problem constants
#define BB   4
#define TT   4096
#define DIMD 1024
#define HH   16
#define DHD  64
#define NROWS (BB * TT)      // 16384

// ---------------------------------------------------------------------------
// Tiled fp32 GEMM: C[M=16384, N=1024] = A[M,1024] @ W[1024,1024]
// 128x128 tile, BK=16, 256 threads, 8x8 microtile.
// AMODE: 0 = A is f32, 1 = A is bf16
// OMODE: 0 = store bf16 (no bias), 1 = store f32 with bias add
// ---------------------------------------------------------------------------
template <int AMODE, int OMODE>
__global__ __launch_bounds__(256) void gemm_k(const void* __restrict__ Ap,
                                              const float* __restrict__ W,
                                              const float* __restrict__ bias,
                                              void* __restrict__ Cp) {
  __shared__ float As[16][132];  // [k][m], padded to keep float4 alignment
  __shared__ float Bs[16][132];  // [k][n]

  const int t    = threadIdx.x;
  const int row0 = blockIdx.y * 128;
  const int col0 = blockIdx.x * 128;
  const int tm   = t >> 4;        // 0..15 -> rows tm*8..tm*8+7
  const int tn   = t & 15;        // 0..15 -> cols tn*8..tn*8+7

  // staging indices
  const int lr   = t >> 1;        // 0..127 : A row within tile
  const int lk   = (t & 1) * 8;   // 0 or 8 : A k-offset
  const int bkr  = t >> 4;        // 0..15  : B k-row
  const int bnc  = (t & 15) * 8;  // 0..120 : B col-offset

  float acc[8][8];
#pragma unroll
  for (int i = 0; i < 8; ++i)
#pragma unroll
    for (int j = 0; j < 8; ++j) acc[i][j] = 0.0f;

  for (int kk = 0; kk < 1024; kk += 16) {
    float av8[8];
    if constexpr (AMODE == 0) {
      const float* ap = (const float*)Ap + (size_t)(row0 + lr) * 1024 + kk + lk;
      float4 a0 = *(const float4*)ap;
      float4 a1 = *(const float4*)(ap + 4);
      av8[0] = a0.x; av8[1] = a0.y; av8[2] = a0.z; av8[3] = a0.w;
      av8[4] = a1.x; av8[5] = a1.y; av8[6] = a1.z; av8[7] = a1.w;
    } else {
      const __hip_bfloat16* ap =
          (const __hip_bfloat16*)Ap + (size_t)(row0 + lr) * 1024 + kk + lk;
      int4 aa = *(const int4*)ap;  // 8 bf16
      const __hip_bfloat16* p = (const __hip_bfloat16*)&aa;
#pragma unroll
      for (int j = 0; j < 8; ++j) av8[j] = __bfloat162float(p[j]);
    }
    const float* bp = W + (size_t)(kk + bkr) * 1024 + col0 + bnc;
    float4 b0 = *(const float4*)bp;
    float4 b1 = *(const float4*)(bp + 4);

    __syncthreads();  // previous iteration's reads complete
#pragma unroll
    for (int j = 0; j < 8; ++j) As[lk + j][lr] = av8[j];
    *(float4*)&Bs[bkr][bnc]     = b0;
    *(float4*)&Bs[bkr][bnc + 4] = b1;
    __syncthreads();

#pragma unroll
    for (int k = 0; k < 16; ++k) {
      float4 x0 = *(float4*)&As[k][tm * 8];
      float4 x1 = *(float4*)&As[k][tm * 8 + 4];
      float4 y0 = *(float4*)&Bs[k][tn * 8];
      float4 y1 = *(float4*)&Bs[k][tn * 8 + 4];
      float a[8] = {x0.x, x0.y, x0.z, x0.w, x1.x, x1.y, x1.z, x1.w};
      float b[8] = {y0.x, y0.y, y0.z, y0.w, y1.x, y1.y, y1.z, y1.w};
#pragma unroll
      for (int i = 0; i < 8; ++i)
#pragma unroll
        for (int j = 0; j < 8; ++j) acc[i][j] += a[i] * b[j];
    }
  }

  if constexpr (OMODE == 0) {
    __hip_bfloat16* C = (__hip_bfloat16*)Cp;
#pragma unroll
    for (int i = 0; i < 8; ++i) {
      const size_t r = (size_t)(row0 + tm * 8 + i);
#pragma unroll
      for (int j = 0; j < 8; ++j)
        C[r * 1024 + col0 + tn * 8 + j] = __float2bfloat16(acc[i][j]);
    }
  } else {
    float* C = (float*)Cp;
    float bv[8];
#pragma unroll
    for (int j = 0; j < 8; ++j) bv[j] = bias[col0 + tn * 8 + j];
#pragma unroll
    for (int i = 0; i < 8; ++i) {
      const size_t r = (size_t)(row0 + tm * 8 + i);
#pragma unroll
      for (int j = 0; j < 8; ++j)
        C[r * 1024 + col0 + tn * 8 + j] = acc[i][j] + bv[j];
    }
  }
}

// ---------------------------------------------------------------------------
// context partials: for (b,h), rows n0..n0+127:
//   part[bh][s][d][e]   += exp(kraw[n][d]) * v[n][e]
//   part[bh][s][64*64+d] = sum_n exp(kraw[n][d])       (denominator partial)
// grid (64, 32), 256 threads
// ---------------------------------------------------------------------------
__global__ __launch_bounds__(256) void ctx_partial_k(
    const __hip_bfloat16* __restrict__ kraw,
    const __hip_bfloat16* __restrict__ vmat, float* __restrict__ part) {
  const int bh = blockIdx.x;
  const int s  = blockIdx.y;
  const int b  = bh >> 4;
  const int h  = bh & 15;
  const int n0 = s * 128;

  __shared__ float ek[128][64];
  __shared__ float vf[128][64];

  const int t  = threadIdx.x;
  const int rr = t >> 1;
  const int c0 = (t & 1) * 32;
  const size_t base = (size_t)(b * TT + n0 + rr) * 1024 + h * 64 + c0;
#pragma unroll
  for (int i = 0; i < 4; ++i) {
    int4 kq = *(const int4*)(kraw + base + i * 8);
    int4 vq = *(const int4*)(vmat + base + i * 8);
    const __hip_bfloat16* kp = (const __hip_bfloat16*)&kq;
    const __hip_bfloat16* vp = (const __hip_bfloat16*)&vq;
#pragma unroll
    for (int j = 0; j < 8; ++j) {
      ek[rr][c0 + i * 8 + j] = __expf(__bfloat162float(kp[j]));
      vf[rr][c0 + i * 8 + j] = __bfloat162float(vp[j]);
    }
  }
  __syncthreads();

  const int d  = t >> 2;
  const int e0 = (t & 3) * 16;
  float acc[16];
#pragma unroll
  for (int j = 0; j < 16; ++j) acc[j] = 0.0f;

  for (int n = 0; n < 128; ++n) {
    const float w = ek[n][d];
    const float4 v0 = *(const float4*)&vf[n][e0];
    const float4 v1 = *(const float4*)&vf[n][e0 + 4];
    const float4 v2 = *(const float4*)&vf[n][e0 + 8];
    const float4 v3 = *(const float4*)&vf[n][e0 + 12];
    acc[0]  += w * v0.x; acc[1]  += w * v0.y; acc[2]  += w * v0.z; acc[3]  += w * v0.w;
    acc[4]  += w * v1.x; acc[5]  += w * v1.y; acc[6]  += w * v1.z; acc[7]  += w * v1.w;
    acc[8]  += w * v2.x; acc[9]  += w * v2.y; acc[10] += w * v2.z; acc[11] += w * v2.w;
    acc[12] += w * v3.x; acc[13] += w * v3.y; acc[14] += w * v3.z; acc[15] += w * v3.w;
  }

  float* pb = part + (size_t)(bh * 32 + s) * 4160;  // 65*64
#pragma unroll
  for (int j = 0; j < 16; ++j) pb[d * 64 + e0 + j] = acc[j];

  if (t < 64) {
    float sden = 0.0f;
    for (int n = 0; n < 128; ++n) sden += ek[n][t];
    pb[4096 + t] = sden;
  }
}

// ---------------------------------------------------------------------------
// context reduce + normalize: ctx[bh][d][e] = sum_s part / sum_s denom[d]
// grid 64, 256 threads
// ---------------------------------------------------------------------------
__global__ __launch_bounds__(256) void ctx_reduce_k(const float* __restrict__ part,
                                                    float* __restrict__ ctx) {
  const int bh = blockIdx.x;
  const int t  = threadIdx.x;
  __shared__ float den[64];
  const float* pb = part + (size_t)bh * 32 * 4160;
  if (t < 64) {
    float sden = 0.0f;
    for (int i = 0; i < 32; ++i) sden += pb[(size_t)i * 4160 + 4096 + t];
    den[t] = 1.0f / sden;
  }
  __syncthreads();
  const int d  = t >> 2;
  const int e0 = (t & 3) * 16;
  const float dinv = den[d];
#pragma unroll
  for (int j = 0; j < 16; ++j) {
    float sv = 0.0f;
    for (int i = 0; i < 32; ++i) sv += pb[(size_t)i * 4160 + d * 64 + e0 + j];
    ctx[(size_t)bh * 4096 + d * 64 + e0 + j] = sv * dinv;
  }
}

// ---------------------------------------------------------------------------
// q softmax (+ * DH^-0.5) and attn = qsm @ ctx   per (128-row chunk, head)
// grid (128, 16), 256 threads
// ---------------------------------------------------------------------------
__global__ __launch_bounds__(256) void qctx_k(const __hip_bfloat16* __restrict__ qraw,
                                              const float* __restrict__ ctx,
                                              __hip_bfloat16* __restrict__ attn) {
  const int rc = blockIdx.x;
  const int h  = blockIdx.y;
  const int n0 = rc * 128;
  const int b  = n0 >> 12;  // /4096

  __shared__ float ctxL[64][64];
  __shared__ float qs[128][64];

  const int t = threadIdx.x;
  // stage context (4096 floats)
  const float4* cp = (const float4*)(ctx + (size_t)(b * HH + h) * 4096);
  float4* cl = (float4*)ctxL;
#pragma unroll
  for (int i = 0; i < 4; ++i) cl[t + 256 * i] = cp[t + 256 * i];

  // per-row softmax over 64 dims: one wave row at a time
  const int w = t >> 6, l = t & 63;
  for (int i = 0; i < 32; ++i) {
    const int r = w * 32 + i;
    float val =
        __bfloat162float(qraw[(size_t)(n0 + r) * 1024 + h * 64 + l]);
    float m = val;
#pragma unroll
    for (int off = 32; off; off >>= 1) m = fmaxf(m, __shfl_xor(m, off));
    float e = __expf(val - m);
    float ssum = e;
#pragma unroll
    for (int off = 32; off; off >>= 1) ssum += __shfl_xor(ssum, off);
    qs[r][l] = e / ssum * 0.125f;
  }
  __syncthreads();

  const int e  = t & 63;
  const int wv = t >> 6;
  for (int i = 0; i < 32; ++i) {
    const int r = i * 4 + wv;
    float acc = 0.0f;
#pragma unroll
    for (int d = 0; d < 64; ++d) acc += qs[r][d] * ctxL[d][e];
    attn[(size_t)(n0 + r) * 1024 + h * 64 + e] = __float2bfloat16(acc);
  }
}

// ---------------------------------------------------------------------------
extern "C" void kernel_launch(void* const* d_in, const int* in_sizes, int n_in,
                              void* d_out, int out_size, void* d_ws,
                              size_t ws_size, hipStream_t stream) {
  const float* x  = (const float*)d_in[0];
  const float* Wq = (const float*)d_in[1];
  const float* Wk = (const float*)d_in[2];
  const float* Wv = (const float*)d_in[3];
  const float* Wo = (const float*)d_in[4];
  const float* bo = (const float*)d_in[5];
  float* out = (float*)d_out;

  char* ws = (char*)d_ws;
  // layout (bytes):
  //   qraw bf16 [16384][1024] : 0   .. 32MB
  //   kraw bf16               : 32  .. 64MB
  //   v    bf16               : 64  .. 96MB
  //   part f32 [64][32][4160] : 96MB .. 96MB+34,078,720   (dead after reduce)
  //   attn bf16 (overlays part): 96 .. 128MB              (written after)
  //   ctx  f32 [64][4096]     : 96MB+34,078,720 .. +1MB
  __hip_bfloat16* qraw = (__hip_bfloat16*)(ws);
  __hip_bfloat16* kraw = (__hip_bfloat16*)(ws + (size_t)(32u << 20));
  __hip_bfloat16* vmat = (__hip_bfloat16*)(ws + (size_t)(64u << 20));
  __hip_bfloat16* attn = (__hip_bfloat16*)(ws + (size_t)(96u << 20));
  float* part = (float*)(ws + (size_t)(96u << 20));
  float* ctx  = (float*)(ws + (size_t)(96u << 20) + (size_t)64 * 32 * 4160 * 4);

  const dim3 blk(256);
  const dim3 gg(1024 / 128, NROWS / 128);  // (8,128)

  gemm_k<0, 0><<<gg, blk, 0, stream>>>(x, Wq, nullptr, qraw);
  gemm_k<0, 0><<<gg, blk, 0, stream>>>(x, Wk, nullptr, kraw);
  gemm_k<0, 0><<<gg, blk, 0, stream>>>(x, Wv, nullptr, vmat);

  ctx_partial_k<<<dim3(64, 32), blk, 0, stream>>>(kraw, vmat, part);
  ctx_reduce_k<<<dim3(64), blk, 0, stream>>>(part, ctx);

  qctx_k<<<dim3(128, 16), blk, 0, stream>>>(qraw, ctx, attn);

  gemm_k<1, 1><<<gg, blk, 0, stream>>>(attn, Wo, bo, out);
}

// Round 2
// 446.496 us; speedup vs baseline: 3.8055x; 3.8055x over previous
//
#include <hip/hip_runtime.h>
#include <hip/hip_bf16.h>
#include <cstdint>
#include <cstddef>

#define BB 4
#define TT 4096
#define HH 16
#define NROWS 16384  // B*T

typedef __attribute__((ext_vector_type(8))) short bf16x8;
typedef __attribute__((ext_vector_type(4))) float f32x4;

__device__ __forceinline__ void gload_lds16(const void* g, void* l) {
  __builtin_amdgcn_global_load_lds(
      (const __attribute__((address_space(1))) void*)g,
      (__attribute__((address_space(3))) void*)l, 16, 0, 0);
}

// ---------------------------------------------------------------------------
// x (f32) -> bf16, 8 elems/thread
// ---------------------------------------------------------------------------
__global__ __launch_bounds__(256) void xconv_k(const float* __restrict__ x,
                                               __hip_bfloat16* __restrict__ xb) {
  const size_t i = ((size_t)blockIdx.x * 256 + threadIdx.x) * 8;
  float4 a = *(const float4*)&x[i];
  float4 b = *(const float4*)&x[i + 4];
  __hip_bfloat16 o[8] __attribute__((aligned(16)));
  o[0] = __float2bfloat16(a.x); o[1] = __float2bfloat16(a.y);
  o[2] = __float2bfloat16(a.z); o[3] = __float2bfloat16(a.w);
  o[4] = __float2bfloat16(b.x); o[5] = __float2bfloat16(b.y);
  o[6] = __float2bfloat16(b.z); o[7] = __float2bfloat16(b.w);
  *(int4*)&xb[i] = *(const int4*)o;
}

// ---------------------------------------------------------------------------
// W [1024][1024] f32 -> WT bf16 [1024][1024] transposed; 4 matrices packed:
// WT rows [0,1024)=Wq^T [1024,2048)=Wk^T [2048,3072)=Wv^T [3072,4096)=Wo^T
// grid (16,16,4) x 256
// ---------------------------------------------------------------------------
__global__ __launch_bounds__(256) void wconv_k(const float* __restrict__ Wq,
                                               const float* __restrict__ Wk,
                                               const float* __restrict__ Wv,
                                               const float* __restrict__ Wo,
                                               __hip_bfloat16* __restrict__ WT) {
  const int which = blockIdx.z;
  const float* W = which == 0 ? Wq : which == 1 ? Wk : which == 2 ? Wv : Wo;
  __shared__ float tile[64][65];
  const int n0 = blockIdx.x * 64, k0 = blockIdx.y * 64;
  const int t = threadIdx.x;
  const int r = t >> 2;          // 0..63
  const int cq = (t & 3) * 16;   // 0,16,32,48
#pragma unroll
  for (int i = 0; i < 4; ++i) {
    float4 v = *(const float4*)&W[(size_t)(k0 + r) * 1024 + n0 + cq + i * 4];
    tile[r][cq + i * 4 + 0] = v.x;
    tile[r][cq + i * 4 + 1] = v.y;
    tile[r][cq + i * 4 + 2] = v.z;
    tile[r][cq + i * 4 + 3] = v.w;
  }
  __syncthreads();
  __hip_bfloat16 ob[16] __attribute__((aligned(16)));
#pragma unroll
  for (int j = 0; j < 16; ++j) ob[j] = __float2bfloat16(tile[cq + j][r]);
  __hip_bfloat16* dst = WT + (size_t)(which * 1024 + n0 + r) * 1024 + k0 + cq;
  *(int4*)dst = *(const int4*)&ob[0];
  *(int4*)(dst + 8) = *(const int4*)&ob[8];
}

// ---------------------------------------------------------------------------
// MFMA bf16 GEMM: C[M,N] = A[M,K=1024] @ BT[N,K=1024]^T
// 128x128 tile, BK=64, 256 thr (4 waves, 2x2), 4x4 16x16x32 frags per wave.
// OMODE 0: bf16 store; OMODE 1: f32 store + bias.
// ---------------------------------------------------------------------------
template <int OMODE>
__global__ __launch_bounds__(256) void mgemm_k(
    const __hip_bfloat16* __restrict__ A, int lda,
    const __hip_bfloat16* __restrict__ BT, const float* __restrict__ bias,
    void* __restrict__ Cp, int ldc) {
  __shared__ __hip_bfloat16 As[128][64];
  __shared__ __hip_bfloat16 Bs[128][64];

  const int t = threadIdx.x;
  const int w = t >> 6, l = t & 63;
  const int wr = w >> 1, wc = w & 1;
  const int row0 = blockIdx.y * 128;
  const int col0 = blockIdx.x * 128;
  const int sr = l >> 3;          // row within wave's 8-row staging group
  const int sc = (l & 7) * 8;     // k-element offset (16B per lane)

  f32x4 acc[4][4];
#pragma unroll
  for (int m = 0; m < 4; ++m)
#pragma unroll
    for (int n = 0; n < 4; ++n) acc[m][n] = (f32x4){0.f, 0.f, 0.f, 0.f};

  const int lr = l & 15;
  const int lk0 = (l >> 4) * 8;

  for (int kk = 0; kk < 1024; kk += 64) {
    __syncthreads();  // previous tile's LDS reads complete
#pragma unroll
    for (int i = 0; i < 4; ++i) {
      const int rA = i * 32 + w * 8;  // wave-uniform base row
      gload_lds16(A + (size_t)(row0 + rA + sr) * lda + kk + sc, &As[rA][0]);
    }
#pragma unroll
    for (int i = 0; i < 4; ++i) {
      const int rB = i * 32 + w * 8;
      gload_lds16(BT + (size_t)(col0 + rB + sr) * 1024 + kk + sc, &Bs[rB][0]);
    }
    __syncthreads();  // staging complete (vmcnt drained at barrier)

#pragma unroll
    for (int kk2 = 0; kk2 < 2; ++kk2) {
      const int lk = kk2 * 32 + lk0;
      bf16x8 af[4], bfv[4];
#pragma unroll
      for (int m = 0; m < 4; ++m)
        af[m] = *(const bf16x8*)&As[wr * 64 + m * 16 + lr][lk];
#pragma unroll
      for (int n = 0; n < 4; ++n)
        bfv[n] = *(const bf16x8*)&Bs[wc * 64 + n * 16 + lr][lk];
#pragma unroll
      for (int m = 0; m < 4; ++m)
#pragma unroll
        for (int n = 0; n < 4; ++n)
          acc[m][n] = __builtin_amdgcn_mfma_f32_16x16x32_bf16(
              af[m], bfv[n], acc[m][n], 0, 0, 0);
    }
  }

  const int cr = (l >> 4) * 4;  // C row base within frag
  const int cc = l & 15;        // C col within frag
  if constexpr (OMODE == 0) {
    __hip_bfloat16* C = (__hip_bfloat16*)Cp;
#pragma unroll
    for (int m = 0; m < 4; ++m)
#pragma unroll
      for (int n = 0; n < 4; ++n) {
        const size_t cb =
            (size_t)(row0 + wr * 64 + m * 16 + cr) * ldc + col0 + wc * 64 + n * 16 + cc;
#pragma unroll
        for (int j = 0; j < 4; ++j)
          C[cb + (size_t)j * ldc] = __float2bfloat16(acc[m][n][j]);
      }
  } else {
    float* C = (float*)Cp;
    float bv[4];
#pragma unroll
    for (int n = 0; n < 4; ++n) bv[n] = bias[col0 + wc * 64 + n * 16 + cc];
#pragma unroll
    for (int m = 0; m < 4; ++m)
#pragma unroll
      for (int n = 0; n < 4; ++n) {
        const size_t cb =
            (size_t)(row0 + wr * 64 + m * 16 + cr) * ldc + col0 + wc * 64 + n * 16 + cc;
#pragma unroll
        for (int j = 0; j < 4; ++j)
          C[cb + (size_t)j * ldc] = acc[m][n][j] + bv[n];
      }
  }
}

// ---------------------------------------------------------------------------
// context partials over 128-row chunks:
//   part[bh][s][d][e] = sum_n exp(k[n][d]) * v[n][e]
//   den[bh][s][d]     = sum_n exp(k[n][d])
// qkv layout: row stride 3072, cols [1024,2048)=k, [2048,3072)=v
// grid (64,32) x 256
// ---------------------------------------------------------------------------
__global__ __launch_bounds__(256) void ctx_partial_k(
    const __hip_bfloat16* __restrict__ qkv, float* __restrict__ part,
    float* __restrict__ den) {
  const int bh = blockIdx.x;
  const int s = blockIdx.y;
  const int b = bh >> 4;
  const int h = bh & 15;
  const int n0 = s * 128;

  __shared__ float ek[128][64];
  __shared__ float vf[128][64];

  const int t = threadIdx.x;
  const int rr = t >> 1;
  const int c0 = (t & 1) * 32;
  const size_t base = (size_t)(b * TT + n0 + rr) * 3072 + 1024 + h * 64 + c0;
#pragma unroll
  for (int i = 0; i < 4; ++i) {
    int4 kq = *(const int4*)(qkv + base + i * 8);
    int4 vq = *(const int4*)(qkv + base + 1024 + i * 8);
    const __hip_bfloat16* kp = (const __hip_bfloat16*)&kq;
    const __hip_bfloat16* vp = (const __hip_bfloat16*)&vq;
#pragma unroll
    for (int j = 0; j < 8; ++j) {
      ek[rr][c0 + i * 8 + j] = __expf(__bfloat162float(kp[j]));
      vf[rr][c0 + i * 8 + j] = __bfloat162float(vp[j]);
    }
  }
  __syncthreads();

  const int d = t >> 2;
  const int e0 = (t & 3) * 16;
  float acc[16];
#pragma unroll
  for (int j = 0; j < 16; ++j) acc[j] = 0.0f;

  for (int n = 0; n < 128; ++n) {
    const float wgt = ek[n][d];
    const float4 v0 = *(const float4*)&vf[n][e0];
    const float4 v1 = *(const float4*)&vf[n][e0 + 4];
    const float4 v2 = *(const float4*)&vf[n][e0 + 8];
    const float4 v3 = *(const float4*)&vf[n][e0 + 12];
    acc[0] += wgt * v0.x;  acc[1] += wgt * v0.y;
    acc[2] += wgt * v0.z;  acc[3] += wgt * v0.w;
    acc[4] += wgt * v1.x;  acc[5] += wgt * v1.y;
    acc[6] += wgt * v1.z;  acc[7] += wgt * v1.w;
    acc[8] += wgt * v2.x;  acc[9] += wgt * v2.y;
    acc[10] += wgt * v2.z; acc[11] += wgt * v2.w;
    acc[12] += wgt * v3.x; acc[13] += wgt * v3.y;
    acc[14] += wgt * v3.z; acc[15] += wgt * v3.w;
  }

  float* pb = part + ((size_t)bh * 32 + s) * 4096;
#pragma unroll
  for (int j = 0; j < 16; ++j) pb[d * 64 + e0 + j] = acc[j];

  if (t < 64) {
    float sden = 0.0f;
    for (int n = 0; n < 128; ++n) sden += ek[n][t];
    den[((size_t)bh * 32 + s) * 64 + t] = sden;
  }
}

// ---------------------------------------------------------------------------
// ctx[bh][d][e] = (sum_s part) / (sum_s den[d]);  grid 64 x 256
// ---------------------------------------------------------------------------
__global__ __launch_bounds__(256) void ctx_reduce_k(const float* __restrict__ part,
                                                    const float* __restrict__ den,
                                                    float* __restrict__ ctx) {
  const int bh = blockIdx.x;
  const int t = threadIdx.x;
  __shared__ float dinvs[64];
  if (t < 64) {
    float sden = 0.0f;
    for (int i = 0; i < 32; ++i) sden += den[((size_t)bh * 32 + i) * 64 + t];
    dinvs[t] = 1.0f / sden;
  }
  __syncthreads();
  const int d = t >> 2;
  const int e0 = (t & 3) * 16;
  const float dinv = dinvs[d];
  const float* pb = part + (size_t)bh * 32 * 4096;
#pragma unroll
  for (int j = 0; j < 16; ++j) {
    float sv = 0.0f;
    for (int i = 0; i < 32; ++i) sv += pb[(size_t)i * 4096 + d * 64 + e0 + j];
    ctx[(size_t)bh * 4096 + d * 64 + e0 + j] = sv * dinv;
  }
}

// ---------------------------------------------------------------------------
// q softmax (*DH^-0.5) and attn = qsm @ ctx, written IN PLACE over q cols.
// grid (128,16) x 256
// ---------------------------------------------------------------------------
__global__ __launch_bounds__(256) void qctx_k(__hip_bfloat16* __restrict__ qkv,
                                              const float* __restrict__ ctx) {
  const int rc = blockIdx.x;
  const int h = blockIdx.y;
  const int n0 = rc * 128;
  const int b = n0 >> 12;

  __shared__ float ctxL[64][64];
  __shared__ float qs[128][64];

  const int t = threadIdx.x;
  const float4* cp = (const float4*)(ctx + (size_t)(b * HH + h) * 4096);
  float4* cl = (float4*)ctxL;
#pragma unroll
  for (int i = 0; i < 4; ++i) cl[t + 256 * i] = cp[t + 256 * i];

  const int w = t >> 6, l = t & 63;
  for (int i = 0; i < 32; ++i) {
    const int r = w * 32 + i;
    float val = __bfloat162float(qkv[(size_t)(n0 + r) * 3072 + h * 64 + l]);
    float m = val;
#pragma unroll
    for (int off = 32; off; off >>= 1) m = fmaxf(m, __shfl_xor(m, off));
    float e = __expf(val - m);
    float ssum = e;
#pragma unroll
    for (int off = 32; off; off >>= 1) ssum += __shfl_xor(ssum, off);
    qs[r][l] = e / ssum * 0.125f;
  }
  __syncthreads();

  const int e = t & 63;
  const int wv = t >> 6;
  for (int i = 0; i < 32; ++i) {
    const int r = i * 4 + wv;
    float acc = 0.0f;
#pragma unroll
    for (int d = 0; d < 64; ++d) acc += qs[r][d] * ctxL[d][e];
    qkv[(size_t)(n0 + r) * 3072 + h * 64 + e] = __float2bfloat16(acc);
  }
}

// ---------------------------------------------------------------------------
extern "C" void kernel_launch(void* const* d_in, const int* in_sizes, int n_in,
                              void* d_out, int out_size, void* d_ws,
                              size_t ws_size, hipStream_t stream) {
  const float* x = (const float*)d_in[0];
  const float* Wq = (const float*)d_in[1];
  const float* Wk = (const float*)d_in[2];
  const float* Wv = (const float*)d_in[3];
  const float* Wo = (const float*)d_in[4];
  const float* bo = (const float*)d_in[5];
  float* out = (float*)d_out;

  // ws layout: qkv bf16 [16384][3072] (96MB) | WT bf16 [4096][1024] (8MB)
  //            | den f32 [64][32][64] (512KB) | ctx f32 [64][4096] (1MB)
  char* ws = (char*)d_ws;
  __hip_bfloat16* qkv = (__hip_bfloat16*)ws;
  __hip_bfloat16* WT = (__hip_bfloat16*)(ws + 100663296ull);
  float* den = (float*)(ws + 100663296ull + 8388608ull);
  float* ctx = (float*)(ws + 100663296ull + 8388608ull + 524288ull);
  // d_out (64MB) doubles as scratch, fully overwritten by the final GEMM:
  //   [0,32MB) xb bf16 [16384][1024]; [32,64MB) part f32 [64][32][4096]
  __hip_bfloat16* xb = (__hip_bfloat16*)d_out;
  float* part = (float*)((char*)d_out + 33554432ull);

  const dim3 blk(256);

  xconv_k<<<dim3(NROWS * 1024 / 8 / 256), blk, 0, stream>>>(x, xb);
  wconv_k<<<dim3(16, 16, 4), blk, 0, stream>>>(Wq, Wk, Wv, Wo, WT);

  // QKV projection: [16384,3072] = xb @ [Wq|Wk|Wv]
  mgemm_k<0><<<dim3(3072 / 128, NROWS / 128), blk, 0, stream>>>(
      xb, 1024, WT, nullptr, qkv, 3072);

  ctx_partial_k<<<dim3(64, 32), blk, 0, stream>>>(qkv, part, den);
  ctx_reduce_k<<<dim3(64), blk, 0, stream>>>(part, den, ctx);
  qctx_k<<<dim3(128, 16), blk, 0, stream>>>(qkv, ctx);

  // out = attn @ Wo + bo   (attn = q cols of qkv, lda 3072)
  mgemm_k<1><<<dim3(1024 / 128, NROWS / 128), blk, 0, stream>>>(
      qkv, 3072, WT + 3072ull * 1024, bo, out, 1024);
}

// Round 3
// 347.094 us; speedup vs baseline: 4.8954x; 1.2864x over previous
//
#include <hip/hip_runtime.h>
#include <hip/hip_bf16.h>
#include <cstdint>
#include <cstddef>

#define BB 4
#define TT 4096
#define HH 16
#define NROWS 16384  // B*T

typedef __attribute__((ext_vector_type(8))) short bf16x8;
typedef __attribute__((ext_vector_type(4))) float f32x4;

__device__ __forceinline__ void gload_lds16(const void* g, void* l) {
  __builtin_amdgcn_global_load_lds(
      (const __attribute__((address_space(1))) void*)g,
      (__attribute__((address_space(3))) void*)l, 16, 0, 0);
}

template <int N>
__device__ __forceinline__ void wait_vmcnt() {
  if constexpr (N == 8)
    asm volatile("s_waitcnt vmcnt(8)" ::: "memory");
  else if constexpr (N == 4)
    asm volatile("s_waitcnt vmcnt(4)" ::: "memory");
  else
    asm volatile("s_waitcnt vmcnt(0)" ::: "memory");
  __builtin_amdgcn_sched_barrier(0);
}

__device__ __forceinline__ void hbar() {
  asm volatile("s_barrier" ::: "memory");
  __builtin_amdgcn_sched_barrier(0);
}

// ---------------------------------------------------------------------------
// x (f32) -> bf16, 8 elems/thread
// ---------------------------------------------------------------------------
__global__ __launch_bounds__(256) void xconv_k(const float* __restrict__ x,
                                               __hip_bfloat16* __restrict__ xb) {
  const size_t i = ((size_t)blockIdx.x * 256 + threadIdx.x) * 8;
  float4 a = *(const float4*)&x[i];
  float4 b = *(const float4*)&x[i + 4];
  __hip_bfloat16 o[8] __attribute__((aligned(16)));
  o[0] = __float2bfloat16(a.x); o[1] = __float2bfloat16(a.y);
  o[2] = __float2bfloat16(a.z); o[3] = __float2bfloat16(a.w);
  o[4] = __float2bfloat16(b.x); o[5] = __float2bfloat16(b.y);
  o[6] = __float2bfloat16(b.z); o[7] = __float2bfloat16(b.w);
  *(int4*)&xb[i] = *(const int4*)o;
}

// ---------------------------------------------------------------------------
// W [1024][1024] f32 -> WT bf16 transposed; 4 matrices packed.
// ---------------------------------------------------------------------------
__global__ __launch_bounds__(256) void wconv_k(const float* __restrict__ Wq,
                                               const float* __restrict__ Wk,
                                               const float* __restrict__ Wv,
                                               const float* __restrict__ Wo,
                                               __hip_bfloat16* __restrict__ WT) {
  const int which = blockIdx.z;
  const float* W = which == 0 ? Wq : which == 1 ? Wk : which == 2 ? Wv : Wo;
  __shared__ float tile[64][65];
  const int n0 = blockIdx.x * 64, k0 = blockIdx.y * 64;
  const int t = threadIdx.x;
  const int r = t >> 2;
  const int cq = (t & 3) * 16;
#pragma unroll
  for (int i = 0; i < 4; ++i) {
    float4 v = *(const float4*)&W[(size_t)(k0 + r) * 1024 + n0 + cq + i * 4];
    tile[r][cq + i * 4 + 0] = v.x;
    tile[r][cq + i * 4 + 1] = v.y;
    tile[r][cq + i * 4 + 2] = v.z;
    tile[r][cq + i * 4 + 3] = v.w;
  }
  __syncthreads();
  __hip_bfloat16 ob[16] __attribute__((aligned(16)));
#pragma unroll
  for (int j = 0; j < 16; ++j) ob[j] = __float2bfloat16(tile[cq + j][r]);
  __hip_bfloat16* dst = WT + (size_t)(which * 1024 + n0 + r) * 1024 + k0 + cq;
  *(int4*)dst = *(const int4*)&ob[0];
  *(int4*)(dst + 8) = *(const int4*)&ob[8];
}

// ---------------------------------------------------------------------------
// MFMA bf16 GEMM, 256x256 tile, BK=32, ring-4 LDS, counted vmcnt.
// 512 threads = 8 waves (2M x 4N); per-wave output 128x64 (8x4 16x16 frags).
// K = 1024 fixed -> NT = 32 K-tiles.
// Hazard model: one barrier per K-tile. Write-after-read: tile kt's ds_reads
// are consumed by its MFMAs (compiler lgkmcnt) before the next barrier, and
// slot (kt+3)&3's staging is issued after that barrier. Read-after-write:
// vmcnt(8) at top of kt = (4*min(kt+3,32) issued) - (4*(kt+1) needed); tails
// peel to vmcnt(4)/vmcnt(0). NO other vmem ops inside the loop (spill-free
// by keeping ~170 VGPR).
// ---------------------------------------------------------------------------
template <int OMODE>
__global__ __launch_bounds__(512) void mgemm2_k(
    const __hip_bfloat16* __restrict__ A, int lda,
    const __hip_bfloat16* __restrict__ BT, const float* __restrict__ bias,
    void* __restrict__ Cp, int ldc, int gx) {
  // ring slot: A [256][32] at 0, B [256][32] at 8192 (elems); 32KB/slot
  __shared__ __hip_bfloat16 lds[4][16384];

  const int t = threadIdx.x;
  const int wid = t >> 6, l = t & 63;
  const int wr = wid >> 2, wc = wid & 3;

  // XCD-bijective swizzle (gridDim.x % 8 == 0 for both call sites)
  const int nwg = gridDim.x;
  const int cpx = nwg >> 3;
  const int bid = blockIdx.x;
  const int swz = (bid & 7) * cpx + (bid >> 3);
  const int bx = swz % gx, by = swz / gx;
  const int row0 = by * 256, col0 = bx * 256;

  // staging: lane l covers row (wid*16 + l>>2), k-elems (l&3)*8 (16B)
  const int srow = l >> 2, skel = (l & 3) * 8;
  const __hip_bfloat16* Ab = A + (size_t)(row0 + wid * 16 + srow) * lda + skel;
  const __hip_bfloat16* Bb = BT + (size_t)(col0 + wid * 16 + srow) * 1024 + skel;

  f32x4 acc[8][4];
#pragma unroll
  for (int m = 0; m < 8; ++m)
#pragma unroll
    for (int n = 0; n < 4; ++n) acc[m][n] = (f32x4){0.f, 0.f, 0.f, 0.f};

  const int lr = l & 15, hk = l >> 4;
  const int aoff = (wr * 128 + lr) * 32 + hk * 8;        // + m*512
  const int boff = 8192 + (wc * 64 + lr) * 32 + hk * 8;  // + n*512

  auto stage = [&](int kt, int slot) {
    const int kk = kt * 32;
    __hip_bfloat16* s = &lds[slot][0];
    gload_lds16(Ab + kk, s + wid * 512);
    gload_lds16(Ab + (size_t)128 * lda + kk, s + 4096 + wid * 512);
    gload_lds16(Bb + kk, s + 8192 + wid * 512);
    gload_lds16(Bb + (size_t)128 * 1024 + kk, s + 12288 + wid * 512);
  };

  auto compute = [&](int slot) {
    const __hip_bfloat16* s = &lds[slot][0];
    bf16x8 bf[4];
#pragma unroll
    for (int n = 0; n < 4; ++n) bf[n] = *(const bf16x8*)(s + boff + n * 512);
    __builtin_amdgcn_s_setprio(1);
#pragma unroll
    for (int m = 0; m < 8; ++m) {
      bf16x8 af = *(const bf16x8*)(s + aoff + m * 512);
#pragma unroll
      for (int n = 0; n < 4; ++n)
        acc[m][n] = __builtin_amdgcn_mfma_f32_16x16x32_bf16(af, bf[n],
                                                            acc[m][n], 0, 0, 0);
    }
    __builtin_amdgcn_s_setprio(0);
  };

  stage(0, 0);
  stage(1, 1);
  stage(2, 2);
  for (int kt = 0; kt < 29; ++kt) {
    wait_vmcnt<8>();
    hbar();
    stage(kt + 3, (kt + 3) & 3);
    compute(kt & 3);
  }
  wait_vmcnt<8>(); hbar(); compute(1);  // kt=29
  wait_vmcnt<4>(); hbar(); compute(2);  // kt=30
  wait_vmcnt<0>(); hbar(); compute(3);  // kt=31

  const int cr = hk * 4;  // acc row base within frag
  const int cc = lr;      // col within frag
  if constexpr (OMODE == 0) {
    __hip_bfloat16* C = (__hip_bfloat16*)Cp;
#pragma unroll
    for (int m = 0; m < 8; ++m)
#pragma unroll
      for (int n = 0; n < 4; ++n) {
        const size_t cb = (size_t)(row0 + wr * 128 + m * 16 + cr) * ldc +
                          col0 + wc * 64 + n * 16 + cc;
#pragma unroll
        for (int j = 0; j < 4; ++j)
          C[cb + (size_t)j * ldc] = __float2bfloat16(acc[m][n][j]);
      }
  } else {
    float* C = (float*)Cp;
    float bv[4];
#pragma unroll
    for (int n = 0; n < 4; ++n) bv[n] = bias[col0 + wc * 64 + n * 16 + cc];
#pragma unroll
    for (int m = 0; m < 8; ++m)
#pragma unroll
      for (int n = 0; n < 4; ++n) {
        const size_t cb = (size_t)(row0 + wr * 128 + m * 16 + cr) * ldc +
                          col0 + wc * 64 + n * 16 + cc;
#pragma unroll
        for (int j = 0; j < 4; ++j)
          C[cb + (size_t)j * ldc] = acc[m][n][j] + bv[n];
      }
  }
}

// ---------------------------------------------------------------------------
// context partials; 4d x 4e register microtile, bank-even lane mapping.
//   part[bh][s][d][e] = sum_n exp(k[n][d]) * v[n][e]; den likewise.
// grid (64,32) x 256
// ---------------------------------------------------------------------------
__global__ __launch_bounds__(256) void ctx_partial_k(
    const __hip_bfloat16* __restrict__ qkv, float* __restrict__ part,
    float* __restrict__ den) {
  const int bh = blockIdx.x;
  const int s = blockIdx.y;
  const int b = bh >> 4;
  const int h = bh & 15;
  const int n0 = s * 128;

  __shared__ float ek[128][64];
  __shared__ float vf[128][64];

  const int t = threadIdx.x;
  const int rr = t >> 1;
  const int c0 = (t & 1) * 32;
  const size_t base = (size_t)(b * TT + n0 + rr) * 3072 + 1024 + h * 64 + c0;
#pragma unroll
  for (int i = 0; i < 4; ++i) {
    int4 kq = *(const int4*)(qkv + base + i * 8);
    int4 vq = *(const int4*)(qkv + base + 1024 + i * 8);
    const __hip_bfloat16* kp = (const __hip_bfloat16*)&kq;
    const __hip_bfloat16* vp = (const __hip_bfloat16*)&vq;
#pragma unroll
    for (int j = 0; j < 8; ++j) {
      ek[rr][c0 + i * 8 + j] = __expf(__bfloat162float(kp[j]));
      vf[rr][c0 + i * 8 + j] = __bfloat162float(vp[j]);
    }
  }
  __syncthreads();

  // bijective t -> (dblk, eblk), each wave bank-even on both reads
  const int lane = t & 63, w = t >> 6;
  const int dblk = (lane & 7) | ((w & 1) << 3);
  const int eblk = (lane >> 3) | ((w >> 1) << 3);
  const int d0 = dblk * 4, e0 = eblk * 4;

  float acc[4][4];
#pragma unroll
  for (int i = 0; i < 4; ++i)
#pragma unroll
    for (int j = 0; j < 4; ++j) acc[i][j] = 0.f;

  for (int n = 0; n < 128; ++n) {
    float4 ekv = *(const float4*)&ek[n][d0];
    float4 vv = *(const float4*)&vf[n][e0];
    acc[0][0] += ekv.x * vv.x; acc[0][1] += ekv.x * vv.y;
    acc[0][2] += ekv.x * vv.z; acc[0][3] += ekv.x * vv.w;
    acc[1][0] += ekv.y * vv.x; acc[1][1] += ekv.y * vv.y;
    acc[1][2] += ekv.y * vv.z; acc[1][3] += ekv.y * vv.w;
    acc[2][0] += ekv.z * vv.x; acc[2][1] += ekv.z * vv.y;
    acc[2][2] += ekv.z * vv.z; acc[2][3] += ekv.z * vv.w;
    acc[3][0] += ekv.w * vv.x; acc[3][1] += ekv.w * vv.y;
    acc[3][2] += ekv.w * vv.z; acc[3][3] += ekv.w * vv.w;
  }

  float* pb = part + ((size_t)bh * 32 + s) * 4096;
#pragma unroll
  for (int di = 0; di < 4; ++di) {
    float4 o = {acc[di][0], acc[di][1], acc[di][2], acc[di][3]};
    *(float4*)&pb[(d0 + di) * 64 + e0] = o;
  }

  if (t < 64) {
    float sden = 0.0f;
    for (int n = 0; n < 128; ++n) sden += ek[n][t];
    den[((size_t)bh * 32 + s) * 64 + t] = sden;
  }
}

// ---------------------------------------------------------------------------
// ctx[bh][d][e] = (sum_s part) / (sum_s den[d]); grid (64,4) x 256, coalesced
// ---------------------------------------------------------------------------
__global__ __launch_bounds__(256) void ctx_reduce_k(const float* __restrict__ part,
                                                    const float* __restrict__ den,
                                                    float* __restrict__ ctx) {
  const int bh = blockIdx.x, q = blockIdx.y, t = threadIdx.x;
  const int idx = q * 1024 + t * 4;
  const int d = idx >> 6;
  float sden = 0.f;
  for (int s = 0; s < 32; ++s) sden += den[((size_t)bh * 32 + s) * 64 + d];
  float4 sv = {0.f, 0.f, 0.f, 0.f};
  const float* pb = part + (size_t)bh * 32 * 4096 + idx;
  for (int s = 0; s < 32; ++s) {
    float4 v = *(const float4*)(pb + (size_t)s * 4096);
    sv.x += v.x; sv.y += v.y; sv.z += v.z; sv.w += v.w;
  }
  const float di = 1.0f / sden;
  sv.x *= di; sv.y *= di; sv.z *= di; sv.w *= di;
  *(float4*)(ctx + (size_t)bh * 4096 + idx) = sv;
}

// ---------------------------------------------------------------------------
// q softmax (*DH^-0.5) and attn = qsm @ ctx, in place over q cols.
// ctx column held in registers (64 VGPR); PV = uniform b128 qs reads + FMA.
// grid (128,16) x 256
// ---------------------------------------------------------------------------
__global__ __launch_bounds__(256) void qctx_k(__hip_bfloat16* __restrict__ qkv,
                                              const float* __restrict__ ctx) {
  const int rc = blockIdx.x;
  const int h = blockIdx.y;
  const int n0 = rc * 128;
  const int b = n0 >> 12;

  __shared__ float ctxT[64][68];  // [e][d], 272B rows -> bank-even col reads
  __shared__ float qs[128][64];

  const int t = threadIdx.x;
  const float* cp = ctx + (size_t)(b * HH + h) * 4096;
#pragma unroll
  for (int i = 0; i < 16; ++i) {
    const int idx = i * 256 + t;
    ctxT[idx & 63][idx >> 6] = cp[idx];
  }

  const int w = t >> 6, l = t & 63;
  for (int i = 0; i < 32; ++i) {
    const int r = w * 32 + i;
    float val = __bfloat162float(qkv[(size_t)(n0 + r) * 3072 + h * 64 + l]);
    float m = val;
#pragma unroll
    for (int off = 32; off; off >>= 1) m = fmaxf(m, __shfl_xor(m, off));
    float e = __expf(val - m);
    float ssum = e;
#pragma unroll
    for (int off = 32; off; off >>= 1) ssum += __shfl_xor(ssum, off);
    qs[r][l] = e / ssum * 0.125f;
  }
  __syncthreads();

  float4 creg[16];
#pragma unroll
  for (int dq = 0; dq < 16; ++dq) creg[dq] = *(const float4*)&ctxT[l][dq * 4];

  for (int i = 0; i < 32; ++i) {
    const int r = w * 32 + i;
    float acc = 0.f;
#pragma unroll
    for (int dq = 0; dq < 16; ++dq) {
      float4 q4 = *(const float4*)&qs[r][dq * 4];
      acc += q4.x * creg[dq].x + q4.y * creg[dq].y + q4.z * creg[dq].z +
             q4.w * creg[dq].w;
    }
    qkv[(size_t)(n0 + r) * 3072 + h * 64 + l] = __float2bfloat16(acc);
  }
}

// ---------------------------------------------------------------------------
extern "C" void kernel_launch(void* const* d_in, const int* in_sizes, int n_in,
                              void* d_out, int out_size, void* d_ws,
                              size_t ws_size, hipStream_t stream) {
  const float* x = (const float*)d_in[0];
  const float* Wq = (const float*)d_in[1];
  const float* Wk = (const float*)d_in[2];
  const float* Wv = (const float*)d_in[3];
  const float* Wo = (const float*)d_in[4];
  const float* bo = (const float*)d_in[5];
  float* out = (float*)d_out;

  // ws: qkv bf16 [16384][3072] (96MB) | WT bf16 [4096][1024] (8MB)
  //     | den f32 (512KB) | ctx f32 (1MB)
  char* ws = (char*)d_ws;
  __hip_bfloat16* qkv = (__hip_bfloat16*)ws;
  __hip_bfloat16* WT = (__hip_bfloat16*)(ws + 100663296ull);
  float* den = (float*)(ws + 100663296ull + 8388608ull);
  float* ctx = (float*)(ws + 100663296ull + 8388608ull + 524288ull);
  // d_out doubles as scratch, fully overwritten by the final GEMM:
  //   [0,32MB) xb bf16; [32,64MB) part f32 [64][32][4096]
  __hip_bfloat16* xb = (__hip_bfloat16*)d_out;
  float* part = (float*)((char*)d_out + 33554432ull);

  const dim3 blk(256);

  xconv_k<<<dim3(NROWS * 1024 / 8 / 256), blk, 0, stream>>>(x, xb);
  wconv_k<<<dim3(16, 16, 4), blk, 0, stream>>>(Wq, Wk, Wv, Wo, WT);

  // QKV projection: [16384,3072] = xb @ [Wq|Wk|Wv] ; 768 blocks (3 passes)
  mgemm2_k<0><<<dim3(768), dim3(512), 0, stream>>>(xb, 1024, WT, nullptr, qkv,
                                                   3072, 12);

  ctx_partial_k<<<dim3(64, 32), blk, 0, stream>>>(qkv, part, den);
  ctx_reduce_k<<<dim3(64, 4), blk, 0, stream>>>(part, den, ctx);
  qctx_k<<<dim3(128, 16), blk, 0, stream>>>(qkv, ctx);

  // out = attn @ Wo + bo ; 256 blocks (1 pass)
  mgemm2_k<1><<<dim3(256), dim3(512), 0, stream>>>(qkv, 3072,
                                                   WT + 3072ull * 1024, bo, out,
                                                   1024, 4);
}

// Round 4
// 228.275 us; speedup vs baseline: 7.4434x; 1.5205x over previous
//
#include <hip/hip_runtime.h>
#include <hip/hip_bf16.h>
#include <cstdint>
#include <cstddef>

#define BB 4
#define TT 4096
#define HH 16
#define NROWS 16384  // B*T

typedef __attribute__((ext_vector_type(8))) short bf16x8;
typedef __attribute__((ext_vector_type(4))) float f32x4;

__device__ __forceinline__ void gload_lds16(const void* g, void* l) {
  __builtin_amdgcn_global_load_lds(
      (const __attribute__((address_space(1))) void*)g,
      (__attribute__((address_space(3))) void*)l, 16, 0, 0);
}

template <int N>
__device__ __forceinline__ void wait_vmcnt() {
  if constexpr (N == 8)
    asm volatile("s_waitcnt vmcnt(8)" ::: "memory");
  else if constexpr (N == 4)
    asm volatile("s_waitcnt vmcnt(4)" ::: "memory");
  else
    asm volatile("s_waitcnt vmcnt(0)" ::: "memory");
  __builtin_amdgcn_sched_barrier(0);
}

__device__ __forceinline__ void hbar() {
  asm volatile("s_barrier" ::: "memory");
  __builtin_amdgcn_sched_barrier(0);
}

// ---------------------------------------------------------------------------
// x (f32) -> bf16, 8 elems/thread
// ---------------------------------------------------------------------------
__global__ __launch_bounds__(256) void xconv_k(const float* __restrict__ x,
                                               __hip_bfloat16* __restrict__ xb) {
  const size_t i = ((size_t)blockIdx.x * 256 + threadIdx.x) * 8;
  float4 a = *(const float4*)&x[i];
  float4 b = *(const float4*)&x[i + 4];
  __hip_bfloat16 o[8] __attribute__((aligned(16)));
  o[0] = __float2bfloat16(a.x); o[1] = __float2bfloat16(a.y);
  o[2] = __float2bfloat16(a.z); o[3] = __float2bfloat16(a.w);
  o[4] = __float2bfloat16(b.x); o[5] = __float2bfloat16(b.y);
  o[6] = __float2bfloat16(b.z); o[7] = __float2bfloat16(b.w);
  *(int4*)&xb[i] = *(const int4*)o;
}

// ---------------------------------------------------------------------------
// W [1024][1024] f32 -> WT bf16 transposed; 4 matrices packed.
// ---------------------------------------------------------------------------
__global__ __launch_bounds__(256) void wconv_k(const float* __restrict__ Wq,
                                               const float* __restrict__ Wk,
                                               const float* __restrict__ Wv,
                                               const float* __restrict__ Wo,
                                               __hip_bfloat16* __restrict__ WT) {
  const int which = blockIdx.z;
  const float* W = which == 0 ? Wq : which == 1 ? Wk : which == 2 ? Wv : Wo;
  __shared__ float tile[64][65];
  const int n0 = blockIdx.x * 64, k0 = blockIdx.y * 64;
  const int t = threadIdx.x;
  const int r = t >> 2;
  const int cq = (t & 3) * 16;
#pragma unroll
  for (int i = 0; i < 4; ++i) {
    float4 v = *(const float4*)&W[(size_t)(k0 + r) * 1024 + n0 + cq + i * 4];
    tile[r][cq + i * 4 + 0] = v.x;
    tile[r][cq + i * 4 + 1] = v.y;
    tile[r][cq + i * 4 + 2] = v.z;
    tile[r][cq + i * 4 + 3] = v.w;
  }
  __syncthreads();
  __hip_bfloat16 ob[16] __attribute__((aligned(16)));
#pragma unroll
  for (int j = 0; j < 16; ++j) ob[j] = __float2bfloat16(tile[cq + j][r]);
  __hip_bfloat16* dst = WT + (size_t)(which * 1024 + n0 + r) * 1024 + k0 + cq;
  *(int4*)dst = *(const int4*)&ob[0];
  *(int4*)(dst + 8) = *(const int4*)&ob[8];
}

// ---------------------------------------------------------------------------
// MFMA bf16 GEMM, 256x256 tile, BK=32, ring-4 LDS, counted vmcnt.
// 512 threads = 8 waves (2M x 4N); per-wave output 128x64.
// PB: B pointer advances by 1M elems per 4096-row batch (fused Wo path).
// ---------------------------------------------------------------------------
template <int OMODE, int PB>
__global__ __launch_bounds__(512) void mgemm2_k(
    const __hip_bfloat16* __restrict__ A, int lda,
    const __hip_bfloat16* __restrict__ BT, const float* __restrict__ bias,
    void* __restrict__ Cp, int ldc, int gx) {
  __shared__ __hip_bfloat16 lds[4][16384];

  const int t = threadIdx.x;
  const int wid = t >> 6, l = t & 63;
  const int wr = wid >> 2, wc = wid & 3;

  const int nwg = gridDim.x;
  const int cpx = nwg >> 3;
  const int bid = blockIdx.x;
  const int swz = (bid & 7) * cpx + (bid >> 3);
  const int bx = swz % gx, by = swz / gx;
  const int row0 = by * 256, col0 = bx * 256;

  const __hip_bfloat16* BTb = PB ? BT + ((size_t)(row0 >> 12) << 20) : BT;

  const int srow = l >> 2, skel = (l & 3) * 8;
  const __hip_bfloat16* Ab = A + (size_t)(row0 + wid * 16 + srow) * lda + skel;
  const __hip_bfloat16* Bb =
      BTb + (size_t)(col0 + wid * 16 + srow) * 1024 + skel;

  f32x4 acc[8][4];
#pragma unroll
  for (int m = 0; m < 8; ++m)
#pragma unroll
    for (int n = 0; n < 4; ++n) acc[m][n] = (f32x4){0.f, 0.f, 0.f, 0.f};

  const int lr = l & 15, hk = l >> 4;
  const int aoff = (wr * 128 + lr) * 32 + hk * 8;
  const int boff = 8192 + (wc * 64 + lr) * 32 + hk * 8;

  auto stage = [&](int kt, int slot) {
    const int kk = kt * 32;
    __hip_bfloat16* s = &lds[slot][0];
    gload_lds16(Ab + kk, s + wid * 512);
    gload_lds16(Ab + (size_t)128 * lda + kk, s + 4096 + wid * 512);
    gload_lds16(Bb + kk, s + 8192 + wid * 512);
    gload_lds16(Bb + (size_t)128 * 1024 + kk, s + 12288 + wid * 512);
  };

  auto compute = [&](int slot) {
    const __hip_bfloat16* s = &lds[slot][0];
    bf16x8 bf[4];
#pragma unroll
    for (int n = 0; n < 4; ++n) bf[n] = *(const bf16x8*)(s + boff + n * 512);
    __builtin_amdgcn_s_setprio(1);
#pragma unroll
    for (int m = 0; m < 8; ++m) {
      bf16x8 af = *(const bf16x8*)(s + aoff + m * 512);
#pragma unroll
      for (int n = 0; n < 4; ++n)
        acc[m][n] = __builtin_amdgcn_mfma_f32_16x16x32_bf16(af, bf[n],
                                                            acc[m][n], 0, 0, 0);
    }
    __builtin_amdgcn_s_setprio(0);
  };

  stage(0, 0);
  stage(1, 1);
  stage(2, 2);
  for (int kt = 0; kt < 29; ++kt) {
    wait_vmcnt<8>();
    hbar();
    stage(kt + 3, (kt + 3) & 3);
    compute(kt & 3);
  }
  wait_vmcnt<8>(); hbar(); compute(1);
  wait_vmcnt<4>(); hbar(); compute(2);
  wait_vmcnt<0>(); hbar(); compute(3);

  const int cr = hk * 4;
  const int cc = lr;
  if constexpr (OMODE == 0) {
    __hip_bfloat16* C = (__hip_bfloat16*)Cp;
#pragma unroll
    for (int m = 0; m < 8; ++m)
#pragma unroll
      for (int n = 0; n < 4; ++n) {
        const size_t cb = (size_t)(row0 + wr * 128 + m * 16 + cr) * ldc +
                          col0 + wc * 64 + n * 16 + cc;
#pragma unroll
        for (int j = 0; j < 4; ++j)
          C[cb + (size_t)j * ldc] = __float2bfloat16(acc[m][n][j]);
      }
  } else {
    float* C = (float*)Cp;
    float bv[4];
#pragma unroll
    for (int n = 0; n < 4; ++n) bv[n] = bias[col0 + wc * 64 + n * 16 + cc];
#pragma unroll
    for (int m = 0; m < 8; ++m)
#pragma unroll
      for (int n = 0; n < 4; ++n) {
        const size_t cb = (size_t)(row0 + wr * 128 + m * 16 + cr) * ldc +
                          col0 + wc * 64 + n * 16 + cc;
#pragma unroll
        for (int j = 0; j < 4; ++j)
          C[cb + (size_t)j * ldc] = acc[m][n][j] + bv[n];
      }
  }
}

// ---------------------------------------------------------------------------
// context partials; 4d x 4e register microtile, bank-even lane mapping.
// grid (64,32) x 256
// ---------------------------------------------------------------------------
__global__ __launch_bounds__(256) void ctx_partial_k(
    const __hip_bfloat16* __restrict__ qkv, float* __restrict__ part,
    float* __restrict__ den) {
  const int bh = blockIdx.x;
  const int s = blockIdx.y;
  const int b = bh >> 4;
  const int h = bh & 15;
  const int n0 = s * 128;

  __shared__ float ek[128][64];
  __shared__ float vf[128][64];

  const int t = threadIdx.x;
  const int rr = t >> 1;
  const int c0 = (t & 1) * 32;
  const size_t base = (size_t)(b * TT + n0 + rr) * 3072 + 1024 + h * 64 + c0;
#pragma unroll
  for (int i = 0; i < 4; ++i) {
    int4 kq = *(const int4*)(qkv + base + i * 8);
    int4 vq = *(const int4*)(qkv + base + 1024 + i * 8);
    const __hip_bfloat16* kp = (const __hip_bfloat16*)&kq;
    const __hip_bfloat16* vp = (const __hip_bfloat16*)&vq;
#pragma unroll
    for (int j = 0; j < 8; ++j) {
      ek[rr][c0 + i * 8 + j] = __expf(__bfloat162float(kp[j]));
      vf[rr][c0 + i * 8 + j] = __bfloat162float(vp[j]);
    }
  }
  __syncthreads();

  const int lane = t & 63, w = t >> 6;
  const int dblk = (lane & 7) | ((w & 1) << 3);
  const int eblk = (lane >> 3) | ((w >> 1) << 3);
  const int d0 = dblk * 4, e0 = eblk * 4;

  float acc[4][4];
#pragma unroll
  for (int i = 0; i < 4; ++i)
#pragma unroll
    for (int j = 0; j < 4; ++j) acc[i][j] = 0.f;

  for (int n = 0; n < 128; ++n) {
    float4 ekv = *(const float4*)&ek[n][d0];
    float4 vv = *(const float4*)&vf[n][e0];
    acc[0][0] += ekv.x * vv.x; acc[0][1] += ekv.x * vv.y;
    acc[0][2] += ekv.x * vv.z; acc[0][3] += ekv.x * vv.w;
    acc[1][0] += ekv.y * vv.x; acc[1][1] += ekv.y * vv.y;
    acc[1][2] += ekv.y * vv.z; acc[1][3] += ekv.y * vv.w;
    acc[2][0] += ekv.z * vv.x; acc[2][1] += ekv.z * vv.y;
    acc[2][2] += ekv.z * vv.z; acc[2][3] += ekv.z * vv.w;
    acc[3][0] += ekv.w * vv.x; acc[3][1] += ekv.w * vv.y;
    acc[3][2] += ekv.w * vv.z; acc[3][3] += ekv.w * vv.w;
  }

  float* pb = part + ((size_t)bh * 32 + s) * 4096;
#pragma unroll
  for (int di = 0; di < 4; ++di) {
    float4 o = {acc[di][0], acc[di][1], acc[di][2], acc[di][3]};
    *(float4*)&pb[(d0 + di) * 64 + e0] = o;
  }

  if (t < 64) {
    float sden = 0.0f;
    for (int n = 0; n < 128; ++n) sden += ek[n][t];
    den[((size_t)bh * 32 + s) * 64 + t] = sden;
  }
}

// ---------------------------------------------------------------------------
// ctxb[bh][d][e] = bf16( (sum_s part) / (sum_s den[d]) ); grid (64,4) x 256
// ---------------------------------------------------------------------------
__global__ __launch_bounds__(256) void ctx_reduce_k(
    const float* __restrict__ part, const float* __restrict__ den,
    __hip_bfloat16* __restrict__ ctxb) {
  const int bh = blockIdx.x, q = blockIdx.y, t = threadIdx.x;
  const int idx = q * 1024 + t * 4;
  const int d = idx >> 6;
  float sden = 0.f;
  for (int s = 0; s < 32; ++s) sden += den[((size_t)bh * 32 + s) * 64 + d];
  float4 sv = {0.f, 0.f, 0.f, 0.f};
  const float* pb = part + (size_t)bh * 32 * 4096 + idx;
  for (int s = 0; s < 32; ++s) {
    float4 v = *(const float4*)(pb + (size_t)s * 4096);
    sv.x += v.x; sv.y += v.y; sv.z += v.z; sv.w += v.w;
  }
  const float di = 1.0f / sden;
  __hip_bfloat16 ob[4] __attribute__((aligned(8)));
  ob[0] = __float2bfloat16(sv.x * di);
  ob[1] = __float2bfloat16(sv.y * di);
  ob[2] = __float2bfloat16(sv.z * di);
  ob[3] = __float2bfloat16(sv.w * di);
  *(int2*)&ctxb[(size_t)bh * 4096 + idx] = *(const int2*)ob;
}

// ---------------------------------------------------------------------------
// q softmax in place: qs = softmax_d(q) * 0.125, bf16. Each 8-lane group
// owns one (row, head); bf16x8 vector I/O; 3-level shfl_xor reduce.
// grid 2048 x 256 (block = 8 rows x 16 heads)
// ---------------------------------------------------------------------------
__global__ __launch_bounds__(256) void qsm_k(__hip_bfloat16* __restrict__ qkv) {
  const int t = threadIdx.x;
  const int w = t >> 6, l = t & 63;
  const int n0 = blockIdx.x * 8;
#pragma unroll
  for (int i = 0; i < 4; ++i) {
    const int u = i * 4 + w;          // 0..15
    const int row = n0 + (u >> 1);
    const int half = u & 1;           // heads [half*8, half*8+8)
    __hip_bfloat16* p = qkv + (size_t)row * 3072 + half * 512 + l * 8;
    int4 raw = *(const int4*)p;
    const __hip_bfloat16* bp = (const __hip_bfloat16*)&raw;
    float v[8];
    float m = -1e30f;
#pragma unroll
    for (int j = 0; j < 8; ++j) {
      v[j] = __bfloat162float(bp[j]);
      m = fmaxf(m, v[j]);
    }
    m = fmaxf(m, __shfl_xor(m, 1));
    m = fmaxf(m, __shfl_xor(m, 2));
    m = fmaxf(m, __shfl_xor(m, 4));
    float s = 0.f;
#pragma unroll
    for (int j = 0; j < 8; ++j) {
      v[j] = __expf(v[j] - m);
      s += v[j];
    }
    s += __shfl_xor(s, 1);
    s += __shfl_xor(s, 2);
    s += __shfl_xor(s, 4);
    const float inv = 0.125f / s;
    __hip_bfloat16 o[8] __attribute__((aligned(16)));
#pragma unroll
    for (int j = 0; j < 8; ++j) o[j] = __float2bfloat16(v[j] * inv);
    *(int4*)p = *(const int4*)o;
  }
}

// ---------------------------------------------------------------------------
// WfT[b][n][k] = sum_e ctx[b][h(k)][k&63][e] * Wo[h*64+e][n]  (bf16, MFMA)
// A[m=n][e] = WoT[n][h*64+e] (from WT rows 3072+), BT[n'=dk][e] = ctxb[dk][e]
// grid (64 bh, 16 n-chunks) x 256 (4 waves x 16 rows)
// ---------------------------------------------------------------------------
__global__ __launch_bounds__(256) void wfuse_k(
    const __hip_bfloat16* __restrict__ WT,
    const __hip_bfloat16* __restrict__ ctxb, __hip_bfloat16* __restrict__ WfT) {
  const int bh = blockIdx.x;
  const int b = bh >> 4, h = bh & 15;
  const int t = threadIdx.x, w = t >> 6, l = t & 63;
  const int n1 = blockIdx.y * 64 + w * 16;
  const int lr = l & 15, hk = l >> 4;

  f32x4 acc[4];
#pragma unroll
  for (int n = 0; n < 4; ++n) acc[n] = (f32x4){0.f, 0.f, 0.f, 0.f};

  const __hip_bfloat16* Abase =
      WT + (size_t)(3072 + n1 + lr) * 1024 + h * 64 + hk * 8;
  const __hip_bfloat16* Bbase = ctxb + (size_t)bh * 4096 + hk * 8;

#pragma unroll
  for (int kk2 = 0; kk2 < 2; ++kk2) {
    bf16x8 af = *(const bf16x8*)(Abase + kk2 * 32);
#pragma unroll
    for (int n = 0; n < 4; ++n) {
      bf16x8 bf = *(const bf16x8*)(Bbase + (n * 16 + lr) * 64 + kk2 * 32);
      acc[n] = __builtin_amdgcn_mfma_f32_16x16x32_bf16(af, bf, acc[n], 0, 0, 0);
    }
  }

  __hip_bfloat16* W0 = WfT + ((size_t)b << 20) + (size_t)(n1 + hk * 4) * 1024 +
                       h * 64 + lr;
#pragma unroll
  for (int n = 0; n < 4; ++n)
#pragma unroll
    for (int j = 0; j < 4; ++j)
      W0[(size_t)j * 1024 + n * 16] = __float2bfloat16(acc[n][j]);
}

// ---------------------------------------------------------------------------
extern "C" void kernel_launch(void* const* d_in, const int* in_sizes, int n_in,
                              void* d_out, int out_size, void* d_ws,
                              size_t ws_size, hipStream_t stream) {
  const float* x = (const float*)d_in[0];
  const float* Wq = (const float*)d_in[1];
  const float* Wk = (const float*)d_in[2];
  const float* Wv = (const float*)d_in[3];
  const float* Wo = (const float*)d_in[4];
  const float* bo = (const float*)d_in[5];
  float* out = (float*)d_out;

  // ws: qkv bf16 [16384][3072] (96MB) | WT bf16 [4096][1024] (8MB)
  //     | den f32 (512KB) | ctxb bf16 (512KB) | WfT bf16 4x[1024][1024] (8MB)
  char* ws = (char*)d_ws;
  __hip_bfloat16* qkv = (__hip_bfloat16*)ws;
  __hip_bfloat16* WT = (__hip_bfloat16*)(ws + 100663296ull);
  float* den = (float*)(ws + 100663296ull + 8388608ull);
  __hip_bfloat16* ctxb =
      (__hip_bfloat16*)(ws + 100663296ull + 8388608ull + 524288ull);
  __hip_bfloat16* WfT =
      (__hip_bfloat16*)(ws + 100663296ull + 8388608ull + 1048576ull);
  // d_out doubles as scratch, fully overwritten by the final GEMM:
  //   [0,32MB) xb bf16; [32,64MB) part f32 [64][32][4096]
  __hip_bfloat16* xb = (__hip_bfloat16*)d_out;
  float* part = (float*)((char*)d_out + 33554432ull);

  const dim3 blk(256);

  xconv_k<<<dim3(NROWS * 1024 / 8 / 256), blk, 0, stream>>>(x, xb);
  wconv_k<<<dim3(16, 16, 4), blk, 0, stream>>>(Wq, Wk, Wv, Wo, WT);

  // QKV projection: [16384,3072] = xb @ [Wq|Wk|Wv]
  mgemm2_k<0, 0><<<dim3(768), dim3(512), 0, stream>>>(xb, 1024, WT, nullptr,
                                                      qkv, 3072, 12);

  ctx_partial_k<<<dim3(64, 32), blk, 0, stream>>>(qkv, part, den);
  ctx_reduce_k<<<dim3(64, 4), blk, 0, stream>>>(part, den, ctxb);
  qsm_k<<<dim3(2048), blk, 0, stream>>>(qkv);
  wfuse_k<<<dim3(64, 16), blk, 0, stream>>>(WT, ctxb, WfT);

  // out = qs @ Wfused[b] + bo
  mgemm2_k<1, 1><<<dim3(256), dim3(512), 0, stream>>>(qkv, 3072, WfT, bo, out,
                                                      1024, 4);
}